// Round 2
// baseline (765.978 us; speedup 1.0000x reference)
//
#include <hip/hip_runtime.h>

#define S_LEN 2048
#define HDIM 4096
#define NHEADS 32
#define HEAD_DIM 128
#define HALF_DIM 64
#define N_QKV 12288
#define QK_COLS 8192

typedef __attribute__((ext_vector_type(8))) short short8;
typedef __attribute__((ext_vector_type(4))) float f32x4;

typedef const __attribute__((address_space(1))) unsigned int gu32;
typedef __attribute__((address_space(3))) unsigned int lu32;

__device__ __forceinline__ void gload_lds16(const void* g, void* l) {
    __builtin_amdgcn_global_load_lds((gu32*)g, (lu32*)l, 16, 0, 0);
}

__device__ __forceinline__ unsigned short f2bf(float f) {
    unsigned int u = __float_as_uint(f);
    u += 0x7fff + ((u >> 16) & 1);
    return (unsigned short)(u >> 16);
}

__device__ __forceinline__ void bar() {
    __builtin_amdgcn_sched_barrier(0);
    __builtin_amdgcn_s_barrier();
    __builtin_amdgcn_sched_barrier(0);
}

// ---------- conversion kernels ----------

__global__ __launch_bounds__(256) void cvt_hs_k(const float* __restrict__ in,
                                                unsigned short* __restrict__ out, int n4) {
    int i = blockIdx.x * 256 + threadIdx.x;
    if (i >= n4) return;
    float4 v = reinterpret_cast<const float4*>(in)[i];
    ushort4 o;
    o.x = f2bf(v.x); o.y = f2bf(v.y); o.z = f2bf(v.z); o.w = f2bf(v.w);
    reinterpret_cast<ushort4*>(out)[i] = o;
}

// column permutation for q/k sections: puts RoPE partner (d, d+64) 16 cols apart
__device__ __forceinline__ int permute_col(int n) {
    if (n < QK_COLS) {
        int hd = n & 127;
        int base = n - hd;
        int e = hd & 63;
        int d2 = (e & 15) + 32 * (e >> 4) + ((hd >> 6) << 4);
        return base + d2;
    }
    return n;
}

// in: [R][C] fp32  ->  out: [perm(C)][R] bf16
template <bool PERM>
__global__ __launch_bounds__(256) void tconv_k(const float* __restrict__ in,
                                               unsigned short* __restrict__ out, int R, int C) {
    __shared__ float tile[64][65];
    int c0 = blockIdx.x * 64, r0 = blockIdx.y * 64;
    int tx = threadIdx.x & 63, ty = threadIdx.x >> 6;
#pragma unroll
    for (int i = 0; i < 16; ++i) {
        int r = ty + i * 4;
        tile[r][tx] = in[(size_t)(r0 + r) * C + c0 + tx];
    }
    __syncthreads();
#pragma unroll
    for (int i = 0; i < 16; ++i) {
        int c = ty + i * 4;
        int n = PERM ? permute_col(c0 + c) : (c0 + c);
        out[(size_t)n * R + r0 + tx] = f2bf(tile[tx][c]);
    }
}

// cos/sin tables: [S][64]
__global__ __launch_bounds__(256) void rope_tab_k(const int* __restrict__ pos_raw,
                                                  float* __restrict__ ctab,
                                                  float* __restrict__ stab) {
    int i = blockIdx.x * 256 + threadIdx.x;  // i < S*64
    int s = i >> 6, d = i & 63;
    bool is64 = (pos_raw[1] == 0 && pos_raw[2] == 1);
    int p = is64 ? pos_raw[2 * s] : pos_raw[s];
    const float INVB = -0.14391156831212787f;  // -2*ln(10000)/128
    float freq = expf((float)d * INVB);
    float th = (float)p * freq;
    ctab[i] = cosf(th);
    stab[i] = sinf(th);
}

// ---------- phased GEMM mainloop: 128x256 tile, BK=64, 8 waves (2M x 4N), per-wave 64x64 ----------
// LDS: A 2x16KB + B 2x32KB = 96KB. T2 swizzle byte^=((row&7)<<4) on both stage-src and ds_read.

__device__ __forceinline__ void mainloop(const unsigned short* __restrict__ Ag,
                                         const unsigned short* __restrict__ Bg,
                                         int K, int m0, int n0,
                                         char* As0, char* As1, char* Bs0, char* Bs1,
                                         f32x4 (&acc)[4][4]) {
    const int tid = threadIdx.x;
    const int wid = tid >> 6, lane = tid & 63, l15 = lane & 15, l4 = lane >> 4;
    const int wm = wid >> 2, wn = wid & 3;
    const int NT = K >> 6;

    size_t abase[2], bbase[4];
    int aoff[2], boff[4];
#pragma unroll
    for (int i = 0; i < 2; ++i) {
        int p = (i * 512 + tid) << 4;
        int q = p ^ (((p >> 7) & 7) << 4);
        abase[i] = (size_t)(m0 + (q >> 7)) * K + ((q & 127) >> 1);
        aoff[i] = p;
    }
#pragma unroll
    for (int i = 0; i < 4; ++i) {
        int p = (i * 512 + tid) << 4;
        int q = p ^ (((p >> 7) & 7) << 4);
        bbase[i] = (size_t)(n0 + (q >> 7)) * K + ((q & 127) >> 1);
        boff[i] = p;
    }

    auto stage = [&](char* Ab, char* Bb, int k0) {
#pragma unroll
        for (int i = 0; i < 2; ++i) gload_lds16(Ag + abase[i] + k0, Ab + aoff[i]);
#pragma unroll
        for (int i = 0; i < 4; ++i) gload_lds16(Bg + bbase[i] + k0, Bb + boff[i]);
    };

    stage(As0, Bs0, 0);
    if (NT > 1) stage(As1, Bs1, 64);

    short8 af[4][2], bf[2][2];

    for (int t = 0; t < NT; ++t) {
        char* Ab = (t & 1) ? As1 : As0;
        char* Bb = (t & 1) ? Bs1 : Bs0;
        if (t + 1 < NT) asm volatile("s_waitcnt vmcnt(6)" ::: "memory");
        else            asm volatile("s_waitcnt vmcnt(0)" ::: "memory");
        bar();  // all waves' stage(t) portions complete -> buf valid

        // ---- phase 0: read all A frags + B(n-half 0); MFMA acc[.][0..1] ----
#pragma unroll
        for (int am = 0; am < 4; ++am)
#pragma unroll
            for (int ks = 0; ks < 2; ++ks) {
                int lin = ((wm * 64 + am * 16 + l15) << 7) + ks * 64 + l4 * 16;
                af[am][ks] = *(const short8*)(Ab + (lin ^ (((lin >> 7) & 7) << 4)));
            }
#pragma unroll
        for (int bn = 0; bn < 2; ++bn)
#pragma unroll
            for (int ks = 0; ks < 2; ++ks) {
                int lin = ((wn * 64 + bn * 16 + l15) << 7) + ks * 64 + l4 * 16;
                bf[bn][ks] = *(const short8*)(Bb + (lin ^ (((lin >> 7) & 7) << 4)));
            }
        bar();
        asm volatile("s_waitcnt lgkmcnt(0)" ::: "memory");
        __builtin_amdgcn_sched_barrier(0);
        __builtin_amdgcn_s_setprio(1);
#pragma unroll
        for (int am = 0; am < 4; ++am)
#pragma unroll
            for (int bn = 0; bn < 2; ++bn)
#pragma unroll
                for (int ks = 0; ks < 2; ++ks)
                    acc[am][bn] = __builtin_amdgcn_mfma_f32_16x16x32_bf16(af[am][ks], bf[bn][ks], acc[am][bn], 0, 0, 0);
        __builtin_amdgcn_s_setprio(0);
        bar();

        // ---- phase 1: read B(n-half 1); MFMA acc[.][2..3] ----
#pragma unroll
        for (int bn = 0; bn < 2; ++bn)
#pragma unroll
            for (int ks = 0; ks < 2; ++ks) {
                int lin = ((wn * 64 + 32 + bn * 16 + l15) << 7) + ks * 64 + l4 * 16;
                bf[bn][ks] = *(const short8*)(Bb + (lin ^ (((lin >> 7) & 7) << 4)));
            }
        bar();
        asm volatile("s_waitcnt lgkmcnt(0)" ::: "memory");
        __builtin_amdgcn_sched_barrier(0);
        __builtin_amdgcn_s_setprio(1);
#pragma unroll
        for (int am = 0; am < 4; ++am)
#pragma unroll
            for (int bn = 0; bn < 2; ++bn)
#pragma unroll
                for (int ks = 0; ks < 2; ++ks)
                    acc[am][bn + 2] = __builtin_amdgcn_mfma_f32_16x16x32_bf16(af[am][ks], bf[bn][ks], acc[am][bn + 2], 0, 0, 0);
        __builtin_amdgcn_s_setprio(0);
        bar();  // all reads of this buffer done -> safe to overwrite

        if (t + 2 < NT) stage(Ab, Bb, (t + 2) << 6);
    }
}

// GEMM1: qkv = hs @ W_qkv(permuted cols), fused RoPE epilogue
__global__ __launch_bounds__(512, 2) void gemm1_k(const unsigned short* __restrict__ A,
                                                  const unsigned short* __restrict__ Bt,
                                                  const float* __restrict__ ctab,
                                                  const float* __restrict__ stab,
                                                  unsigned short* __restrict__ qb,
                                                  unsigned short* __restrict__ kb,
                                                  unsigned short* __restrict__ vt) {
    __shared__ __attribute__((aligned(16))) char As0[16384];
    __shared__ __attribute__((aligned(16))) char As1[16384];
    __shared__ __attribute__((aligned(16))) char Bs0[32768];
    __shared__ __attribute__((aligned(16))) char Bs1[32768];

    int nwg = gridDim.x * gridDim.y;
    int lin = blockIdx.y * gridDim.x + blockIdx.x;
    int cpx = nwg >> 3;
    int w2 = (lin & 7) * cpx + (lin >> 3);
    int bx = w2 % gridDim.x, by = w2 / gridDim.x;
    int m0 = by * 128, n0 = bx * 256;

    f32x4 acc[4][4];
#pragma unroll
    for (int i = 0; i < 4; ++i)
#pragma unroll
        for (int j = 0; j < 4; ++j) acc[i][j] = (f32x4){0.f, 0.f, 0.f, 0.f};

    mainloop(A, Bt, HDIM, m0, n0, As0, As1, Bs0, Bs1, acc);

    int tid = threadIdx.x, wid = tid >> 6, lane = tid & 63, l15 = lane & 15, l4 = lane >> 4;
    int wm = wid >> 2, wn = wid & 3;
    int which = n0 >> 12;  // 0=q 1=k 2=v
    if (which < 2) {
        unsigned short* dst = which ? kb : qb;
        int head = ((n0 & 4095) >> 7) + (wn >> 1);
        int jbb = (wn & 1) << 1;
#pragma unroll
        for (int am = 0; am < 4; ++am)
#pragma unroll
            for (int j = 0; j < 4; ++j) {
                int s = m0 + wm * 64 + am * 16 + l4 * 4 + j;
#pragma unroll
                for (int pp = 0; pp < 2; ++pp) {
                    int d = (jbb + pp) * 16 + l15;
                    float cs = ctab[s * 64 + d], sn = stab[s * 64 + d];
                    float x1 = acc[am][2 * pp][j], x2 = acc[am][2 * pp + 1][j];
                    dst[((size_t)head * S_LEN + s) * HEAD_DIM + d] = f2bf(x1 * cs - x2 * sn);
                    dst[((size_t)head * S_LEN + s) * HEAD_DIM + d + 64] = f2bf(x1 * sn + x2 * cs);
                }
            }
    } else {
#pragma unroll
        for (int am = 0; am < 4; ++am)
#pragma unroll
            for (int j = 0; j < 4; ++j) {
                int s = m0 + wm * 64 + am * 16 + l4 * 4 + j;
#pragma unroll
                for (int bn = 0; bn < 4; ++bn) {
                    int col = (n0 - QK_COLS) + wn * 64 + bn * 16 + l15;
                    int head = col >> 7, d = col & 127;
                    vt[((size_t)head * HEAD_DIM + d) * S_LEN + s] = f2bf(acc[am][bn][j]);
                }
            }
    }
}

// GEMM2: out = ctx @ W_o (fp32 out)
__global__ __launch_bounds__(512, 2) void gemm2_k(const unsigned short* __restrict__ A,
                                                  const unsigned short* __restrict__ Bt,
                                                  float* __restrict__ out) {
    __shared__ __attribute__((aligned(16))) char As0[16384];
    __shared__ __attribute__((aligned(16))) char As1[16384];
    __shared__ __attribute__((aligned(16))) char Bs0[32768];
    __shared__ __attribute__((aligned(16))) char Bs1[32768];

    int nwg = gridDim.x * gridDim.y;
    int lin = blockIdx.y * gridDim.x + blockIdx.x;
    int cpx = nwg >> 3;
    int w2 = (lin & 7) * cpx + (lin >> 3);
    int bx = w2 % gridDim.x, by = w2 / gridDim.x;
    int m0 = by * 128, n0 = bx * 256;

    f32x4 acc[4][4];
#pragma unroll
    for (int i = 0; i < 4; ++i)
#pragma unroll
        for (int j = 0; j < 4; ++j) acc[i][j] = (f32x4){0.f, 0.f, 0.f, 0.f};

    mainloop(A, Bt, HDIM, m0, n0, As0, As1, Bs0, Bs1, acc);

    int tid = threadIdx.x, wid = tid >> 6, lane = tid & 63, l15 = lane & 15, l4 = lane >> 4;
    int wm = wid >> 2, wn = wid & 3;
#pragma unroll
    for (int am = 0; am < 4; ++am)
#pragma unroll
        for (int j = 0; j < 4; ++j) {
            int s = m0 + wm * 64 + am * 16 + l4 * 4 + j;
#pragma unroll
            for (int bn = 0; bn < 4; ++bn)
                out[(size_t)s * HDIM + n0 + wn * 64 + bn * 16 + l15] = acc[am][bn][j];
        }
}

// ---------- flash attention (unchanged from passing round) ----------
__global__ __launch_bounds__(256) void flash_k(const unsigned short* __restrict__ Q,
                                               const unsigned short* __restrict__ Kb,
                                               const unsigned short* __restrict__ Vt,
                                               unsigned short* __restrict__ Ctx) {
    __shared__ __attribute__((aligned(16))) unsigned short Ks[32 * 128];
    __shared__ __attribute__((aligned(16))) unsigned short Vs[128 * 32];
    __shared__ __attribute__((aligned(16))) unsigned short Ps[4][32 * 32];
    int qbk = blockIdx.x, h = blockIdx.y;
    int tid = threadIdx.x, w = tid >> 6, lane = tid & 63, l15 = lane & 15, l4 = lane >> 4;
    int qrow0 = qbk * 128 + w * 32;

    short8 qf[2][4];
#pragma unroll
    for (int mt = 0; mt < 2; ++mt) {
        int s = qrow0 + mt * 16 + l15;
#pragma unroll
        for (int ks = 0; ks < 4; ++ks)
            qf[mt][ks] = *(const short8*)(Q + ((size_t)h * S_LEN + s) * HEAD_DIM + ks * 32 + l4 * 8);
    }

    float m_run[2][4], l_run[2][4];
    f32x4 o[2][8];
#pragma unroll
    for (int mt = 0; mt < 2; ++mt)
#pragma unroll
        for (int j = 0; j < 4; ++j) { m_run[mt][j] = -1e30f; l_run[mt][j] = 0.f; }
#pragma unroll
    for (int mt = 0; mt < 2; ++mt)
#pragma unroll
        for (int dt = 0; dt < 8; ++dt) o[mt][dt] = (f32x4){0.f, 0.f, 0.f, 0.f};

    const float scale = 0.08838834764831845f;  // 1/sqrt(128)
    int ntiles = (qbk + 1) * 4;

    for (int t = 0; t < ntiles; ++t) {
        __syncthreads();
#pragma unroll
        for (int it = 0; it < 2; ++it) {
            int idx = it * 256 + tid;
            int kr = idx >> 4, kc = (idx & 15) << 3;
            gload_lds16(Kb + ((size_t)h * S_LEN + t * 32 + kr) * HEAD_DIM + kc, Ks + idx * 8);
            int vr = idx >> 2, vc = (idx & 3) << 3;
            gload_lds16(Vt + ((size_t)h * HEAD_DIM + vr) * S_LEN + t * 32 + vc, Vs + idx * 8);
        }
        __syncthreads();

        f32x4 sc[2][2];
#pragma unroll
        for (int mt = 0; mt < 2; ++mt)
#pragma unroll
            for (int nt = 0; nt < 2; ++nt) sc[mt][nt] = (f32x4){0.f, 0.f, 0.f, 0.f};
#pragma unroll
        for (int ks = 0; ks < 4; ++ks) {
            short8 kfr[2];
#pragma unroll
            for (int nt = 0; nt < 2; ++nt)
                kfr[nt] = *(const short8*)(Ks + (nt * 16 + l15) * 128 + ks * 32 + l4 * 8);
#pragma unroll
            for (int mt = 0; mt < 2; ++mt)
#pragma unroll
                for (int nt = 0; nt < 2; ++nt)
                    sc[mt][nt] = __builtin_amdgcn_mfma_f32_16x16x32_bf16(qf[mt][ks], kfr[nt], sc[mt][nt], 0, 0, 0);
        }

#pragma unroll
        for (int mt = 0; mt < 2; ++mt)
#pragma unroll
            for (int j = 0; j < 4; ++j) {
                int srow = qrow0 + mt * 16 + l4 * 4 + j;
                float v0 = sc[mt][0][j] * scale;
                float v1 = sc[mt][1][j] * scale;
                int c0 = t * 32 + l15;
                if (c0 > srow) v0 = -1e30f;
                if (c0 + 16 > srow) v1 = -1e30f;
                float mx = fmaxf(v0, v1);
                mx = fmaxf(mx, __shfl_xor(mx, 1));
                mx = fmaxf(mx, __shfl_xor(mx, 2));
                mx = fmaxf(mx, __shfl_xor(mx, 4));
                mx = fmaxf(mx, __shfl_xor(mx, 8));
                float mold = m_run[mt][j];
                float mnew = fmaxf(mold, mx);
                float r = __expf(mold - mnew);
                float p0 = __expf(v0 - mnew);
                float p1 = __expf(v1 - mnew);
                float rs = p0 + p1;
                rs += __shfl_xor(rs, 1);
                rs += __shfl_xor(rs, 2);
                rs += __shfl_xor(rs, 4);
                rs += __shfl_xor(rs, 8);
                m_run[mt][j] = mnew;
                l_run[mt][j] = l_run[mt][j] * r + rs;
#pragma unroll
                for (int dt = 0; dt < 8; ++dt) o[mt][dt][j] *= r;
                int prow = mt * 16 + l4 * 4 + j;
                Ps[w][prow * 32 + l15] = f2bf(p0);
                Ps[w][prow * 32 + l15 + 16] = f2bf(p1);
            }
        __syncthreads();

        short8 pf[2];
#pragma unroll
        for (int mt = 0; mt < 2; ++mt)
            pf[mt] = *(const short8*)(&Ps[w][(mt * 16 + l15) * 32 + l4 * 8]);
#pragma unroll
        for (int dt = 0; dt < 8; ++dt) {
            short8 vf = *(const short8*)(Vs + (dt * 16 + l15) * 32 + l4 * 8);
#pragma unroll
            for (int mt = 0; mt < 2; ++mt)
                o[mt][dt] = __builtin_amdgcn_mfma_f32_16x16x32_bf16(pf[mt], vf, o[mt][dt], 0, 0, 0);
        }
    }

#pragma unroll
    for (int mt = 0; mt < 2; ++mt)
#pragma unroll
        for (int j = 0; j < 4; ++j) {
            float inv = 1.0f / l_run[mt][j];
            int s = qrow0 + mt * 16 + l4 * 4 + j;
#pragma unroll
            for (int dt = 0; dt < 8; ++dt)
                Ctx[(size_t)s * HDIM + h * HEAD_DIM + dt * 16 + l15] = f2bf(o[mt][dt][j] * inv);
        }
}

// ---------- launcher ----------

extern "C" void kernel_launch(void* const* d_in, const int* in_sizes, int n_in,
                              void* d_out, int out_size, void* d_ws, size_t ws_size,
                              hipStream_t stream) {
    const float* hs = (const float*)d_in[0];
    const float* wqkv = (const float*)d_in[1];
    const float* wo = (const float*)d_in[2];
    const int* pos = (const int*)d_in[4];
    float* out = (float*)d_out;
    char* ws = (char*)d_ws;
    const size_t MB = 1024 * 1024;

    unsigned short* hs_b = (unsigned short*)(ws);             // 16 MiB
    unsigned short* wq_t = (unsigned short*)(ws + 16 * MB);   // 96 MiB  [12288][4096] (q/k cols permuted)
    unsigned short* wo_t = (unsigned short*)(ws + 112 * MB);  // 32 MiB  [4096][4096]
    unsigned short* qbuf = (unsigned short*)(ws + 144 * MB);  // 16 MiB  [NH][S][HD]
    unsigned short* kbuf = (unsigned short*)(ws + 160 * MB);  // 16 MiB
    unsigned short* vtb  = (unsigned short*)(ws + 176 * MB);  // 16 MiB  [NH][HD][S]
    unsigned short* ctx  = (unsigned short*)(ws + 192 * MB);  // 16 MiB  [S][H]
    float* ctab = (float*)(ws + 208 * MB);                    // 512 KiB
    float* stab = (float*)(ws + 209 * MB);                    // 512 KiB

    cvt_hs_k<<<(S_LEN * HDIM / 4 + 255) / 256, 256, 0, stream>>>(hs, hs_b, S_LEN * HDIM / 4);
    tconv_k<true><<<dim3(N_QKV / 64, HDIM / 64), 256, 0, stream>>>(wqkv, wq_t, HDIM, N_QKV);
    tconv_k<false><<<dim3(HDIM / 64, HDIM / 64), 256, 0, stream>>>(wo, wo_t, HDIM, HDIM);
    rope_tab_k<<<(S_LEN * 64) / 256, 256, 0, stream>>>(pos, ctab, stab);
    gemm1_k<<<dim3(N_QKV / 256, S_LEN / 128), 512, 0, stream>>>(hs_b, wq_t, ctab, stab, qbuf, kbuf, vtb);
    flash_k<<<dim3(S_LEN / 128, NHEADS), 256, 0, stream>>>(qbuf, kbuf, vtb, ctx);
    gemm2_k<<<dim3(HDIM / 256, S_LEN / 128), 512, 0, stream>>>(ctx, wo_t, out);
}

// Round 3
// 742.827 us; speedup vs baseline: 1.0312x; 1.0312x over previous
//
#include <hip/hip_runtime.h>

#define S_LEN 2048
#define HDIM 4096
#define NHEADS 32
#define HEAD_DIM 128
#define HALF_DIM 64
#define N_QKV 12288
#define QK_COLS 8192

typedef __attribute__((ext_vector_type(8))) short short8;
typedef __attribute__((ext_vector_type(4))) float f32x4;

typedef const __attribute__((address_space(1))) unsigned int gu32;
typedef __attribute__((address_space(3))) unsigned int lu32;

__device__ __forceinline__ void gload_lds16(const void* g, void* l) {
    __builtin_amdgcn_global_load_lds((gu32*)g, (lu32*)l, 16, 0, 0);
}

__device__ __forceinline__ unsigned short f2bf(float f) {
    unsigned int u = __float_as_uint(f);
    u += 0x7fff + ((u >> 16) & 1);
    return (unsigned short)(u >> 16);
}

__device__ __forceinline__ void bar() {
    __builtin_amdgcn_sched_barrier(0);
    __builtin_amdgcn_s_barrier();
    __builtin_amdgcn_sched_barrier(0);
}

// XCD-chunked block remap: XCD x owns a contiguous (gridDim.x/8)-wide bx range,
// bx-fast within the chunk so concurrent blocks share A panels and stream B once.
__device__ __forceinline__ void xcd_map(int& bx, int& by) {
    int gx = gridDim.x;
    int lin = blockIdx.y * gx + blockIdx.x;
    int x = lin & 7, c = lin >> 3;
    int bxp = gx >> 3;  // gridDim.x must be a multiple of 8
    bx = bxp * x + c % bxp;
    by = c / bxp;
}

// ---------- conversion kernels ----------

__global__ __launch_bounds__(256) void cvt_hs_k(const float* __restrict__ in,
                                                unsigned short* __restrict__ out, int n4) {
    int i = blockIdx.x * 256 + threadIdx.x;
    if (i >= n4) return;
    float4 v = reinterpret_cast<const float4*>(in)[i];
    ushort4 o;
    o.x = f2bf(v.x); o.y = f2bf(v.y); o.z = f2bf(v.z); o.w = f2bf(v.w);
    reinterpret_cast<ushort4*>(out)[i] = o;
}

// column permutation for q/k sections: puts RoPE partner (d, d+64) 16 cols apart
__device__ __forceinline__ int permute_col(int n) {
    if (n < QK_COLS) {
        int hd = n & 127;
        int base = n - hd;
        int e = hd & 63;
        int d2 = (e & 15) + 32 * (e >> 4) + ((hd >> 6) << 4);
        return base + d2;
    }
    return n;
}

// in: [R][C] fp32  ->  out: [perm(C)][R] bf16
template <bool PERM>
__global__ __launch_bounds__(256) void tconv_k(const float* __restrict__ in,
                                               unsigned short* __restrict__ out, int R, int C) {
    __shared__ float tile[64][65];
    int c0 = blockIdx.x * 64, r0 = blockIdx.y * 64;
    int tx = threadIdx.x & 63, ty = threadIdx.x >> 6;
#pragma unroll
    for (int i = 0; i < 16; ++i) {
        int r = ty + i * 4;
        tile[r][tx] = in[(size_t)(r0 + r) * C + c0 + tx];
    }
    __syncthreads();
#pragma unroll
    for (int i = 0; i < 16; ++i) {
        int c = ty + i * 4;
        int n = PERM ? permute_col(c0 + c) : (c0 + c);
        out[(size_t)n * R + r0 + tx] = f2bf(tile[tx][c]);
    }
}

// cos/sin tables: [S][64]
__global__ __launch_bounds__(256) void rope_tab_k(const int* __restrict__ pos_raw,
                                                  float* __restrict__ ctab,
                                                  float* __restrict__ stab) {
    int i = blockIdx.x * 256 + threadIdx.x;  // i < S*64
    int s = i >> 6, d = i & 63;
    bool is64 = (pos_raw[1] == 0 && pos_raw[2] == 1);
    int p = is64 ? pos_raw[2 * s] : pos_raw[s];
    const float INVB = -0.14391156831212787f;  // -2*ln(10000)/128
    float freq = expf((float)d * INVB);
    float th = (float)p * freq;
    ctab[i] = cosf(th);
    stab[i] = sinf(th);
}

// ---------- GEMM mainloop: 128x256 tile, BK=64, 8 waves (2M x 4N), per-wave 64x64 ----------
// Triple-buffered LDS (48KB/tile x 3 = 144KB). stage(t+2) issued at TOP of tile t into the
// buffer freed by tile t-1 -> ~2-tile prefetch window with counted vmcnt(12).
// T2 swizzle byte^=((row&7)<<4) applied both-sides (inverse-swizzled global src, swizzled read).

__device__ __forceinline__ void mainloop(const unsigned short* __restrict__ Ag,
                                         const unsigned short* __restrict__ Bg,
                                         int K, int m0, int n0,
                                         char* As, char* Bs,
                                         f32x4 (&acc)[4][4]) {
    const int tid = threadIdx.x;
    const int wid = tid >> 6, lane = tid & 63, l15 = lane & 15, l4 = lane >> 4;
    const int wm = wid >> 2, wn = wid & 3;
    const int NT = K >> 6;

    size_t abase[2]; int aoff[2];
#pragma unroll
    for (int i = 0; i < 2; ++i) {
        int p = (i * 512 + tid) << 4;
        int q = p ^ (((p >> 7) & 7) << 4);
        abase[i] = (size_t)(m0 + (q >> 7)) * K + ((q & 127) >> 1);
        aoff[i] = p;
    }
    size_t bbase[4]; int boff[4];
#pragma unroll
    for (int i = 0; i < 4; ++i) {
        int p = (i * 512 + tid) << 4;
        int q = p ^ (((p >> 7) & 7) << 4);
        bbase[i] = (size_t)(n0 + (q >> 7)) * K + ((q & 127) >> 1);
        boff[i] = p;
    }

    auto stage = [&](int t) {
        char* Ab = As + (t % 3) * 16384;
        char* Bb = Bs + (t % 3) * 32768;
        int k0 = t << 6;
#pragma unroll
        for (int i = 0; i < 2; ++i) gload_lds16(Ag + abase[i] + k0, Ab + aoff[i]);
#pragma unroll
        for (int i = 0; i < 4; ++i) gload_lds16(Bg + bbase[i] + k0, Bb + boff[i]);
    };

    stage(0);
    stage(1);

    short8 af[4][2], bf[2][2];

    for (int t = 0; t < NT; ++t) {
        char* Ab = As + (t % 3) * 16384;
        char* Bb = Bs + (t % 3) * 32768;
        // deep prefetch: issue t+2 into the buffer tile t-1 just vacated, then
        // wait (counted) for tile t's 6 loads; 12 newer loads stay in flight.
        if (t + 2 < NT) {
            stage(t + 2);
            asm volatile("s_waitcnt vmcnt(12)" ::: "memory");
        } else if (t + 1 < NT) {
            asm volatile("s_waitcnt vmcnt(6)" ::: "memory");
        } else {
            asm volatile("s_waitcnt vmcnt(0)" ::: "memory");
        }
        bar();  // tile t fully staged for all waves

        // ---- phase 0: read all A frags + B(n-half 0); MFMA acc[.][0..1] ----
#pragma unroll
        for (int am = 0; am < 4; ++am)
#pragma unroll
            for (int ks = 0; ks < 2; ++ks) {
                int lin = ((wm * 64 + am * 16 + l15) << 7) + ks * 64 + l4 * 16;
                af[am][ks] = *(const short8*)(Ab + (lin ^ (((lin >> 7) & 7) << 4)));
            }
#pragma unroll
        for (int bn = 0; bn < 2; ++bn)
#pragma unroll
            for (int ks = 0; ks < 2; ++ks) {
                int lin = ((wn * 64 + bn * 16 + l15) << 7) + ks * 64 + l4 * 16;
                bf[bn][ks] = *(const short8*)(Bb + (lin ^ (((lin >> 7) & 7) << 4)));
            }
        bar();
        asm volatile("s_waitcnt lgkmcnt(0)" ::: "memory");
        __builtin_amdgcn_sched_barrier(0);
        __builtin_amdgcn_s_setprio(1);
#pragma unroll
        for (int am = 0; am < 4; ++am)
#pragma unroll
            for (int bn = 0; bn < 2; ++bn)
#pragma unroll
                for (int ks = 0; ks < 2; ++ks)
                    acc[am][bn] = __builtin_amdgcn_mfma_f32_16x16x32_bf16(af[am][ks], bf[bn][ks], acc[am][bn], 0, 0, 0);
        __builtin_amdgcn_s_setprio(0);
        bar();

        // ---- phase 1: read B(n-half 1); MFMA acc[.][2..3] ----
#pragma unroll
        for (int bn = 0; bn < 2; ++bn)
#pragma unroll
            for (int ks = 0; ks < 2; ++ks) {
                int lin = ((wn * 64 + 32 + bn * 16 + l15) << 7) + ks * 64 + l4 * 16;
                bf[bn][ks] = *(const short8*)(Bb + (lin ^ (((lin >> 7) & 7) << 4)));
            }
        bar();
        asm volatile("s_waitcnt lgkmcnt(0)" ::: "memory");
        __builtin_amdgcn_sched_barrier(0);
        __builtin_amdgcn_s_setprio(1);
#pragma unroll
        for (int am = 0; am < 4; ++am)
#pragma unroll
            for (int bn = 0; bn < 2; ++bn)
#pragma unroll
                for (int ks = 0; ks < 2; ++ks)
                    acc[am][bn + 2] = __builtin_amdgcn_mfma_f32_16x16x32_bf16(af[am][ks], bf[bn][ks], acc[am][bn + 2], 0, 0, 0);
        __builtin_amdgcn_s_setprio(0);
        bar();  // all reads of buf t%3 done -> next iteration may stage into it
    }
}

// GEMM1: qkv = hs @ W_qkv(permuted cols), fused RoPE epilogue
__global__ __launch_bounds__(512, 2) void gemm1_k(const unsigned short* __restrict__ A,
                                                  const unsigned short* __restrict__ Bt,
                                                  const float* __restrict__ ctab,
                                                  const float* __restrict__ stab,
                                                  unsigned short* __restrict__ qb,
                                                  unsigned short* __restrict__ kb,
                                                  unsigned short* __restrict__ vt) {
    __shared__ __attribute__((aligned(16))) char As[3 * 16384];
    __shared__ __attribute__((aligned(16))) char Bs[3 * 32768];

    int bx, by;
    xcd_map(bx, by);
    int m0 = by * 128, n0 = bx * 256;

    f32x4 acc[4][4];
#pragma unroll
    for (int i = 0; i < 4; ++i)
#pragma unroll
        for (int j = 0; j < 4; ++j) acc[i][j] = (f32x4){0.f, 0.f, 0.f, 0.f};

    mainloop(A, Bt, HDIM, m0, n0, As, Bs, acc);

    int tid = threadIdx.x, wid = tid >> 6, lane = tid & 63, l15 = lane & 15, l4 = lane >> 4;
    int wm = wid >> 2, wn = wid & 3;
    int which = n0 >> 12;  // 0=q 1=k 2=v
    if (which < 2) {
        unsigned short* dst = which ? kb : qb;
        int head = ((n0 & 4095) >> 7) + (wn >> 1);
        int jbb = (wn & 1) << 1;
#pragma unroll
        for (int am = 0; am < 4; ++am)
#pragma unroll
            for (int j = 0; j < 4; ++j) {
                int s = m0 + wm * 64 + am * 16 + l4 * 4 + j;
#pragma unroll
                for (int pp = 0; pp < 2; ++pp) {
                    int d = (jbb + pp) * 16 + l15;
                    float cs = ctab[s * 64 + d], sn = stab[s * 64 + d];
                    float x1 = acc[am][2 * pp][j], x2 = acc[am][2 * pp + 1][j];
                    dst[((size_t)head * S_LEN + s) * HEAD_DIM + d] = f2bf(x1 * cs - x2 * sn);
                    dst[((size_t)head * S_LEN + s) * HEAD_DIM + d + 64] = f2bf(x1 * sn + x2 * cs);
                }
            }
    } else {
#pragma unroll
        for (int am = 0; am < 4; ++am)
#pragma unroll
            for (int j = 0; j < 4; ++j) {
                int s = m0 + wm * 64 + am * 16 + l4 * 4 + j;
#pragma unroll
                for (int bn = 0; bn < 4; ++bn) {
                    int col = (n0 - QK_COLS) + wn * 64 + bn * 16 + l15;
                    int head = col >> 7, d = col & 127;
                    vt[((size_t)head * HEAD_DIM + d) * S_LEN + s] = f2bf(acc[am][bn][j]);
                }
            }
    }
}

// GEMM2: out = ctx @ W_o (fp32 out)
__global__ __launch_bounds__(512, 2) void gemm2_k(const unsigned short* __restrict__ A,
                                                  const unsigned short* __restrict__ Bt,
                                                  float* __restrict__ out) {
    __shared__ __attribute__((aligned(16))) char As[3 * 16384];
    __shared__ __attribute__((aligned(16))) char Bs[3 * 32768];

    int bx, by;
    xcd_map(bx, by);
    int m0 = by * 128, n0 = bx * 256;

    f32x4 acc[4][4];
#pragma unroll
    for (int i = 0; i < 4; ++i)
#pragma unroll
        for (int j = 0; j < 4; ++j) acc[i][j] = (f32x4){0.f, 0.f, 0.f, 0.f};

    mainloop(A, Bt, HDIM, m0, n0, As, Bs, acc);

    int tid = threadIdx.x, wid = tid >> 6, lane = tid & 63, l15 = lane & 15, l4 = lane >> 4;
    int wm = wid >> 2, wn = wid & 3;
#pragma unroll
    for (int am = 0; am < 4; ++am)
#pragma unroll
        for (int j = 0; j < 4; ++j) {
            int s = m0 + wm * 64 + am * 16 + l4 * 4 + j;
#pragma unroll
            for (int bn = 0; bn < 4; ++bn)
                out[(size_t)s * HDIM + n0 + wn * 64 + bn * 16 + l15] = acc[am][bn][j];
        }
}

// ---------- flash attention (frozen) ----------
__global__ __launch_bounds__(256) void flash_k(const unsigned short* __restrict__ Q,
                                               const unsigned short* __restrict__ Kb,
                                               const unsigned short* __restrict__ Vt,
                                               unsigned short* __restrict__ Ctx) {
    __shared__ __attribute__((aligned(16))) unsigned short Ks[32 * 128];
    __shared__ __attribute__((aligned(16))) unsigned short Vs[128 * 32];
    __shared__ __attribute__((aligned(16))) unsigned short Ps[4][32 * 32];
    int qbk = blockIdx.x, h = blockIdx.y;
    int tid = threadIdx.x, w = tid >> 6, lane = tid & 63, l15 = lane & 15, l4 = lane >> 4;
    int qrow0 = qbk * 128 + w * 32;

    short8 qf[2][4];
#pragma unroll
    for (int mt = 0; mt < 2; ++mt) {
        int s = qrow0 + mt * 16 + l15;
#pragma unroll
        for (int ks = 0; ks < 4; ++ks)
            qf[mt][ks] = *(const short8*)(Q + ((size_t)h * S_LEN + s) * HEAD_DIM + ks * 32 + l4 * 8);
    }

    float m_run[2][4], l_run[2][4];
    f32x4 o[2][8];
#pragma unroll
    for (int mt = 0; mt < 2; ++mt)
#pragma unroll
        for (int j = 0; j < 4; ++j) { m_run[mt][j] = -1e30f; l_run[mt][j] = 0.f; }
#pragma unroll
    for (int mt = 0; mt < 2; ++mt)
#pragma unroll
        for (int dt = 0; dt < 8; ++dt) o[mt][dt] = (f32x4){0.f, 0.f, 0.f, 0.f};

    const float scale = 0.08838834764831845f;  // 1/sqrt(128)
    int ntiles = (qbk + 1) * 4;

    for (int t = 0; t < ntiles; ++t) {
        __syncthreads();
#pragma unroll
        for (int it = 0; it < 2; ++it) {
            int idx = it * 256 + tid;
            int kr = idx >> 4, kc = (idx & 15) << 3;
            gload_lds16(Kb + ((size_t)h * S_LEN + t * 32 + kr) * HEAD_DIM + kc, Ks + idx * 8);
            int vr = idx >> 2, vc = (idx & 3) << 3;
            gload_lds16(Vt + ((size_t)h * HEAD_DIM + vr) * S_LEN + t * 32 + vc, Vs + idx * 8);
        }
        __syncthreads();

        f32x4 sc[2][2];
#pragma unroll
        for (int mt = 0; mt < 2; ++mt)
#pragma unroll
            for (int nt = 0; nt < 2; ++nt) sc[mt][nt] = (f32x4){0.f, 0.f, 0.f, 0.f};
#pragma unroll
        for (int ks = 0; ks < 4; ++ks) {
            short8 kfr[2];
#pragma unroll
            for (int nt = 0; nt < 2; ++nt)
                kfr[nt] = *(const short8*)(Ks + (nt * 16 + l15) * 128 + ks * 32 + l4 * 8);
#pragma unroll
            for (int mt = 0; mt < 2; ++mt)
#pragma unroll
                for (int nt = 0; nt < 2; ++nt)
                    sc[mt][nt] = __builtin_amdgcn_mfma_f32_16x16x32_bf16(qf[mt][ks], kfr[nt], sc[mt][nt], 0, 0, 0);
        }

#pragma unroll
        for (int mt = 0; mt < 2; ++mt)
#pragma unroll
            for (int j = 0; j < 4; ++j) {
                int srow = qrow0 + mt * 16 + l4 * 4 + j;
                float v0 = sc[mt][0][j] * scale;
                float v1 = sc[mt][1][j] * scale;
                int c0 = t * 32 + l15;
                if (c0 > srow) v0 = -1e30f;
                if (c0 + 16 > srow) v1 = -1e30f;
                float mx = fmaxf(v0, v1);
                mx = fmaxf(mx, __shfl_xor(mx, 1));
                mx = fmaxf(mx, __shfl_xor(mx, 2));
                mx = fmaxf(mx, __shfl_xor(mx, 4));
                mx = fmaxf(mx, __shfl_xor(mx, 8));
                float mold = m_run[mt][j];
                float mnew = fmaxf(mold, mx);
                float r = __expf(mold - mnew);
                float p0 = __expf(v0 - mnew);
                float p1 = __expf(v1 - mnew);
                float rs = p0 + p1;
                rs += __shfl_xor(rs, 1);
                rs += __shfl_xor(rs, 2);
                rs += __shfl_xor(rs, 4);
                rs += __shfl_xor(rs, 8);
                m_run[mt][j] = mnew;
                l_run[mt][j] = l_run[mt][j] * r + rs;
#pragma unroll
                for (int dt = 0; dt < 8; ++dt) o[mt][dt][j] *= r;
                int prow = mt * 16 + l4 * 4 + j;
                Ps[w][prow * 32 + l15] = f2bf(p0);
                Ps[w][prow * 32 + l15 + 16] = f2bf(p1);
            }
        __syncthreads();

        short8 pf[2];
#pragma unroll
        for (int mt = 0; mt < 2; ++mt)
            pf[mt] = *(const short8*)(&Ps[w][(mt * 16 + l15) * 32 + l4 * 8]);
#pragma unroll
        for (int dt = 0; dt < 8; ++dt) {
            short8 vf = *(const short8*)(Vs + (dt * 16 + l15) * 32 + l4 * 8);
#pragma unroll
            for (int mt = 0; mt < 2; ++mt)
                o[mt][dt] = __builtin_amdgcn_mfma_f32_16x16x32_bf16(pf[mt], vf, o[mt][dt], 0, 0, 0);
        }
    }

#pragma unroll
    for (int mt = 0; mt < 2; ++mt)
#pragma unroll
        for (int j = 0; j < 4; ++j) {
            float inv = 1.0f / l_run[mt][j];
            int s = qrow0 + mt * 16 + l4 * 4 + j;
#pragma unroll
            for (int dt = 0; dt < 8; ++dt)
                Ctx[(size_t)s * HDIM + h * HEAD_DIM + dt * 16 + l15] = f2bf(o[mt][dt][j] * inv);
        }
}

// ---------- launcher ----------

extern "C" void kernel_launch(void* const* d_in, const int* in_sizes, int n_in,
                              void* d_out, int out_size, void* d_ws, size_t ws_size,
                              hipStream_t stream) {
    const float* hs = (const float*)d_in[0];
    const float* wqkv = (const float*)d_in[1];
    const float* wo = (const float*)d_in[2];
    const int* pos = (const int*)d_in[4];
    float* out = (float*)d_out;
    char* ws = (char*)d_ws;
    const size_t MB = 1024 * 1024;

    unsigned short* hs_b = (unsigned short*)(ws);             // 16 MiB
    unsigned short* wq_t = (unsigned short*)(ws + 16 * MB);   // 96 MiB  [12288][4096] (q/k cols permuted)
    unsigned short* wo_t = (unsigned short*)(ws + 112 * MB);  // 32 MiB  [4096][4096]
    unsigned short* qbuf = (unsigned short*)(ws + 144 * MB);  // 16 MiB  [NH][S][HD]
    unsigned short* kbuf = (unsigned short*)(ws + 160 * MB);  // 16 MiB
    unsigned short* vtb  = (unsigned short*)(ws + 176 * MB);  // 16 MiB  [NH][HD][S]
    unsigned short* ctx  = (unsigned short*)(ws + 192 * MB);  // 16 MiB  [S][H]
    float* ctab = (float*)(ws + 208 * MB);                    // 512 KiB
    float* stab = (float*)(ws + 209 * MB);                    // 512 KiB

    cvt_hs_k<<<(S_LEN * HDIM / 4 + 255) / 256, 256, 0, stream>>>(hs, hs_b, S_LEN * HDIM / 4);
    tconv_k<true><<<dim3(N_QKV / 64, HDIM / 64), 256, 0, stream>>>(wqkv, wq_t, HDIM, N_QKV);
    tconv_k<false><<<dim3(HDIM / 64, HDIM / 64), 256, 0, stream>>>(wo, wo_t, HDIM, HDIM);
    rope_tab_k<<<(S_LEN * 64) / 256, 256, 0, stream>>>(pos, ctab, stab);
    gemm1_k<<<dim3(N_QKV / 256, S_LEN / 128), 512, 0, stream>>>(hs_b, wq_t, ctab, stab, qbuf, kbuf, vtb);
    flash_k<<<dim3(S_LEN / 128, NHEADS), 256, 0, stream>>>(qbuf, kbuf, vtb, ctx);
    gemm2_k<<<dim3(HDIM / 256, S_LEN / 128), 512, 0, stream>>>(ctx, wo_t, out);
}

// Round 4
// 693.398 us; speedup vs baseline: 1.1047x; 1.0713x over previous
//
#include <hip/hip_runtime.h>

#define S_LEN 2048
#define HDIM 4096
#define NHEADS 32
#define HEAD_DIM 128
#define HALF_DIM 64
#define N_QKV 12288
#define QK_COLS 8192

typedef __attribute__((ext_vector_type(8))) short short8;
typedef __attribute__((ext_vector_type(4))) float f32x4;

typedef const __attribute__((address_space(1))) unsigned int gu32;
typedef __attribute__((address_space(3))) unsigned int lu32;

__device__ __forceinline__ void gload_lds16(const void* g, void* l) {
    __builtin_amdgcn_global_load_lds((gu32*)g, (lu32*)l, 16, 0, 0);
}

__device__ __forceinline__ unsigned short f2bf(float f) {
    unsigned int u = __float_as_uint(f);
    u += 0x7fff + ((u >> 16) & 1);
    return (unsigned short)(u >> 16);
}

// XCD-chunked block remap (bx-fast within each XCD's contiguous chunk).
__device__ __forceinline__ void xcd_map(int& bx, int& by) {
    int gx = gridDim.x;
    int lin = blockIdx.y * gx + blockIdx.x;
    int x = lin & 7, c = lin >> 3;
    int bxp = gx >> 3;  // gridDim.x must be a multiple of 8
    bx = bxp * x + c % bxp;
    by = c / bxp;
}

// ---------- conversion kernels ----------

__global__ __launch_bounds__(256) void cvt_hs_k(const float* __restrict__ in,
                                                unsigned short* __restrict__ out, int n4) {
    int i = blockIdx.x * 256 + threadIdx.x;
    if (i >= n4) return;
    float4 v = reinterpret_cast<const float4*>(in)[i];
    ushort4 o;
    o.x = f2bf(v.x); o.y = f2bf(v.y); o.z = f2bf(v.z); o.w = f2bf(v.w);
    reinterpret_cast<ushort4*>(out)[i] = o;
}

// in: [R][C] fp32  ->  out: [C][R] bf16
__global__ __launch_bounds__(256) void tconv_k(const float* __restrict__ in,
                                               unsigned short* __restrict__ out, int R, int C) {
    __shared__ float tile[64][65];
    int c0 = blockIdx.x * 64, r0 = blockIdx.y * 64;
    int tx = threadIdx.x & 63, ty = threadIdx.x >> 6;
#pragma unroll
    for (int i = 0; i < 16; ++i) {
        int r = ty + i * 4;
        tile[r][tx] = in[(size_t)(r0 + r) * C + c0 + tx];
    }
    __syncthreads();
#pragma unroll
    for (int i = 0; i < 16; ++i) {
        int c = ty + i * 4;
        out[(size_t)(c0 + c) * R + r0 + tx] = f2bf(tile[tx][c]);
    }
}

// cos/sin tables: [S][64]
__global__ __launch_bounds__(256) void rope_tab_k(const int* __restrict__ pos_raw,
                                                  float* __restrict__ ctab,
                                                  float* __restrict__ stab) {
    int i = blockIdx.x * 256 + threadIdx.x;  // i < S*64
    int s = i >> 6, d = i & 63;
    bool is64 = (pos_raw[1] == 0 && pos_raw[2] == 1);
    int p = is64 ? pos_raw[2 * s] : pos_raw[s];
    const float INVB = -0.14391156831212787f;  // -2*ln(10000)/128
    float freq = expf((float)d * INVB);
    float th = (float)p * freq;
    ctab[i] = cosf(th);
    stab[i] = sinf(th);
}

// ---------- GEMM mainloop (m99-style): 128x128 tile, BK=64, 4 waves, per-wave 32x128 ----------
// Double-buffered LDS 2x(16+16)KB = 64KB -> 2 blocks/CU. ONE barrier + one vmcnt(0) per K-tile;
// ds_read/MFMA interleave left to the compiler (auto counted lgkmcnt). T2 XOR swizzle both-sides.

__device__ __forceinline__ void mainloop(const unsigned short* __restrict__ Ag,
                                         const unsigned short* __restrict__ Bg,
                                         int K, int m0, int n0,
                                         char* As, char* Bs,
                                         f32x4 (&acc)[2][8]) {
    const int tid = threadIdx.x;
    const int wid = tid >> 6, lane = tid & 63, l15 = lane & 15, l4 = lane >> 4;
    const int NT = K >> 6;

    size_t abase[4], bbase[4];
    int off[4];
#pragma unroll
    for (int i = 0; i < 4; ++i) {
        int p = (i * 256 + tid) << 4;           // LDS byte offset 0..16383
        int q = p ^ (((p >> 7) & 7) << 4);      // inverse swizzle on global source
        abase[i] = (size_t)(m0 + (q >> 7)) * K + ((q & 127) >> 1);
        bbase[i] = (size_t)(n0 + (q >> 7)) * K + ((q & 127) >> 1);
        off[i] = p;
    }

    auto stage = [&](int t) {
        char* Ab = As + (t & 1) * 16384;
        char* Bb = Bs + (t & 1) * 16384;
        int k0 = t << 6;
#pragma unroll
        for (int i = 0; i < 4; ++i) gload_lds16(Ag + abase[i] + k0, Ab + off[i]);
#pragma unroll
        for (int i = 0; i < 4; ++i) gload_lds16(Bg + bbase[i] + k0, Bb + off[i]);
    };

    stage(0);

    for (int t = 0; t < NT; ++t) {
        char* Ab = As + (t & 1) * 16384;
        char* Bb = Bs + (t & 1) * 16384;
        // wait for tile t's 8 loads (issued one iteration ago; latency covered by compute t-1),
        // then sync: buf[t&1] valid for all waves, and buf[(t+1)&1]'s old readers are done.
        asm volatile("s_waitcnt vmcnt(0)" ::: "memory");
        __builtin_amdgcn_s_barrier();
        if (t + 1 < NT) stage(t + 1);

        short8 a[2][2], b[8][2];
#pragma unroll
        for (int am = 0; am < 2; ++am)
#pragma unroll
            for (int ks = 0; ks < 2; ++ks) {
                int lin = ((wid * 32 + am * 16 + l15) << 7) + ks * 64 + l4 * 16;
                a[am][ks] = *(const short8*)(Ab + (lin ^ (((lin >> 7) & 7) << 4)));
            }
#pragma unroll
        for (int bn = 0; bn < 8; ++bn)
#pragma unroll
            for (int ks = 0; ks < 2; ++ks) {
                int lin = ((bn * 16 + l15) << 7) + ks * 64 + l4 * 16;
                b[bn][ks] = *(const short8*)(Bb + (lin ^ (((lin >> 7) & 7) << 4)));
            }
#pragma unroll
        for (int ks = 0; ks < 2; ++ks)
#pragma unroll
            for (int am = 0; am < 2; ++am)
#pragma unroll
                for (int bn = 0; bn < 8; ++bn)
                    acc[am][bn] = __builtin_amdgcn_mfma_f32_16x16x32_bf16(a[am][ks], b[bn][ks], acc[am][bn], 0, 0, 0);

        __builtin_amdgcn_s_barrier();  // all reads of buf[t&1] done before t+2 stages into it
    }
}

// GEMM1: qkv = hs @ W_qkv, fused RoPE epilogue; per-wave span = 128 cols = one head
__global__ __launch_bounds__(256, 2) void gemm1_k(const unsigned short* __restrict__ A,
                                                  const unsigned short* __restrict__ Bt,
                                                  const float* __restrict__ ctab,
                                                  const float* __restrict__ stab,
                                                  unsigned short* __restrict__ qb,
                                                  unsigned short* __restrict__ kb,
                                                  unsigned short* __restrict__ vt) {
    __shared__ __attribute__((aligned(16))) char As[2 * 16384];
    __shared__ __attribute__((aligned(16))) char Bs[2 * 16384];

    int bx, by;
    xcd_map(bx, by);
    int m0 = by * 128, n0 = bx * 128;

    f32x4 acc[2][8];
#pragma unroll
    for (int i = 0; i < 2; ++i)
#pragma unroll
        for (int j = 0; j < 8; ++j) acc[i][j] = (f32x4){0.f, 0.f, 0.f, 0.f};

    mainloop(A, Bt, HDIM, m0, n0, As, Bs, acc);

    int tid = threadIdx.x, wid = tid >> 6, lane = tid & 63, l15 = lane & 15, l4 = lane >> 4;
    int which = n0 >> 12;  // 0=q 1=k 2=v
    int head = (n0 & 4095) >> 7;
    if (which < 2) {
        unsigned short* dst = which ? kb : qb;
#pragma unroll
        for (int am = 0; am < 2; ++am)
#pragma unroll
            for (int j = 0; j < 4; ++j) {
                int s = m0 + wid * 32 + am * 16 + l4 * 4 + j;
#pragma unroll
                for (int nt = 0; nt < 4; ++nt) {
                    int d = nt * 16 + l15;
                    float cs = ctab[s * 64 + d], sn = stab[s * 64 + d];
                    float x1 = acc[am][nt][j], x2 = acc[am][nt + 4][j];
                    dst[((size_t)head * S_LEN + s) * HEAD_DIM + d] = f2bf(x1 * cs - x2 * sn);
                    dst[((size_t)head * S_LEN + s) * HEAD_DIM + d + 64] = f2bf(x1 * sn + x2 * cs);
                }
            }
    } else {
#pragma unroll
        for (int am = 0; am < 2; ++am)
#pragma unroll
            for (int j = 0; j < 4; ++j) {
                int s = m0 + wid * 32 + am * 16 + l4 * 4 + j;
#pragma unroll
                for (int nt = 0; nt < 8; ++nt) {
                    int d = nt * 16 + l15;
                    vt[((size_t)head * HEAD_DIM + d) * S_LEN + s] = f2bf(acc[am][nt][j]);
                }
            }
    }
}

// GEMM2: out = ctx @ W_o (fp32 out)
__global__ __launch_bounds__(256, 2) void gemm2_k(const unsigned short* __restrict__ A,
                                                  const unsigned short* __restrict__ Bt,
                                                  float* __restrict__ out) {
    __shared__ __attribute__((aligned(16))) char As[2 * 16384];
    __shared__ __attribute__((aligned(16))) char Bs[2 * 16384];

    int bx, by;
    xcd_map(bx, by);
    int m0 = by * 128, n0 = bx * 128;

    f32x4 acc[2][8];
#pragma unroll
    for (int i = 0; i < 2; ++i)
#pragma unroll
        for (int j = 0; j < 8; ++j) acc[i][j] = (f32x4){0.f, 0.f, 0.f, 0.f};

    mainloop(A, Bt, HDIM, m0, n0, As, Bs, acc);

    int tid = threadIdx.x, wid = tid >> 6, lane = tid & 63, l15 = lane & 15, l4 = lane >> 4;
#pragma unroll
    for (int am = 0; am < 2; ++am)
#pragma unroll
        for (int j = 0; j < 4; ++j) {
            int s = m0 + wid * 32 + am * 16 + l4 * 4 + j;
#pragma unroll
            for (int nt = 0; nt < 8; ++nt)
                out[(size_t)s * HDIM + n0 + nt * 16 + l15] = acc[am][nt][j];
        }
}

// ---------- flash attention (frozen) ----------
__global__ __launch_bounds__(256) void flash_k(const unsigned short* __restrict__ Q,
                                               const unsigned short* __restrict__ Kb,
                                               const unsigned short* __restrict__ Vt,
                                               unsigned short* __restrict__ Ctx) {
    __shared__ __attribute__((aligned(16))) unsigned short Ks[32 * 128];
    __shared__ __attribute__((aligned(16))) unsigned short Vs[128 * 32];
    __shared__ __attribute__((aligned(16))) unsigned short Ps[4][32 * 32];
    int qbk = blockIdx.x, h = blockIdx.y;
    int tid = threadIdx.x, w = tid >> 6, lane = tid & 63, l15 = lane & 15, l4 = lane >> 4;
    int qrow0 = qbk * 128 + w * 32;

    short8 qf[2][4];
#pragma unroll
    for (int mt = 0; mt < 2; ++mt) {
        int s = qrow0 + mt * 16 + l15;
#pragma unroll
        for (int ks = 0; ks < 4; ++ks)
            qf[mt][ks] = *(const short8*)(Q + ((size_t)h * S_LEN + s) * HEAD_DIM + ks * 32 + l4 * 8);
    }

    float m_run[2][4], l_run[2][4];
    f32x4 o[2][8];
#pragma unroll
    for (int mt = 0; mt < 2; ++mt)
#pragma unroll
        for (int j = 0; j < 4; ++j) { m_run[mt][j] = -1e30f; l_run[mt][j] = 0.f; }
#pragma unroll
    for (int mt = 0; mt < 2; ++mt)
#pragma unroll
        for (int dt = 0; dt < 8; ++dt) o[mt][dt] = (f32x4){0.f, 0.f, 0.f, 0.f};

    const float scale = 0.08838834764831845f;  // 1/sqrt(128)
    int ntiles = (qbk + 1) * 4;

    for (int t = 0; t < ntiles; ++t) {
        __syncthreads();
#pragma unroll
        for (int it = 0; it < 2; ++it) {
            int idx = it * 256 + tid;
            int kr = idx >> 4, kc = (idx & 15) << 3;
            gload_lds16(Kb + ((size_t)h * S_LEN + t * 32 + kr) * HEAD_DIM + kc, Ks + idx * 8);
            int vr = idx >> 2, vc = (idx & 3) << 3;
            gload_lds16(Vt + ((size_t)h * HEAD_DIM + vr) * S_LEN + t * 32 + vc, Vs + idx * 8);
        }
        __syncthreads();

        f32x4 sc[2][2];
#pragma unroll
        for (int mt = 0; mt < 2; ++mt)
#pragma unroll
            for (int nt = 0; nt < 2; ++nt) sc[mt][nt] = (f32x4){0.f, 0.f, 0.f, 0.f};
#pragma unroll
        for (int ks = 0; ks < 4; ++ks) {
            short8 kfr[2];
#pragma unroll
            for (int nt = 0; nt < 2; ++nt)
                kfr[nt] = *(const short8*)(Ks + (nt * 16 + l15) * 128 + ks * 32 + l4 * 8);
#pragma unroll
            for (int mt = 0; mt < 2; ++mt)
#pragma unroll
                for (int nt = 0; nt < 2; ++nt)
                    sc[mt][nt] = __builtin_amdgcn_mfma_f32_16x16x32_bf16(qf[mt][ks], kfr[nt], sc[mt][nt], 0, 0, 0);
        }

#pragma unroll
        for (int mt = 0; mt < 2; ++mt)
#pragma unroll
            for (int j = 0; j < 4; ++j) {
                int srow = qrow0 + mt * 16 + l4 * 4 + j;
                float v0 = sc[mt][0][j] * scale;
                float v1 = sc[mt][1][j] * scale;
                int c0 = t * 32 + l15;
                if (c0 > srow) v0 = -1e30f;
                if (c0 + 16 > srow) v1 = -1e30f;
                float mx = fmaxf(v0, v1);
                mx = fmaxf(mx, __shfl_xor(mx, 1));
                mx = fmaxf(mx, __shfl_xor(mx, 2));
                mx = fmaxf(mx, __shfl_xor(mx, 4));
                mx = fmaxf(mx, __shfl_xor(mx, 8));
                float mold = m_run[mt][j];
                float mnew = fmaxf(mold, mx);
                float r = __expf(mold - mnew);
                float p0 = __expf(v0 - mnew);
                float p1 = __expf(v1 - mnew);
                float rs = p0 + p1;
                rs += __shfl_xor(rs, 1);
                rs += __shfl_xor(rs, 2);
                rs += __shfl_xor(rs, 4);
                rs += __shfl_xor(rs, 8);
                m_run[mt][j] = mnew;
                l_run[mt][j] = l_run[mt][j] * r + rs;
#pragma unroll
                for (int dt = 0; dt < 8; ++dt) o[mt][dt][j] *= r;
                int prow = mt * 16 + l4 * 4 + j;
                Ps[w][prow * 32 + l15] = f2bf(p0);
                Ps[w][prow * 32 + l15 + 16] = f2bf(p1);
            }
        __syncthreads();

        short8 pf[2];
#pragma unroll
        for (int mt = 0; mt < 2; ++mt)
            pf[mt] = *(const short8*)(&Ps[w][(mt * 16 + l15) * 32 + l4 * 8]);
#pragma unroll
        for (int dt = 0; dt < 8; ++dt) {
            short8 vf = *(const short8*)(Vs + (dt * 16 + l15) * 32 + l4 * 8);
#pragma unroll
            for (int mt = 0; mt < 2; ++mt)
                o[mt][dt] = __builtin_amdgcn_mfma_f32_16x16x32_bf16(pf[mt], vf, o[mt][dt], 0, 0, 0);
        }
    }

#pragma unroll
    for (int mt = 0; mt < 2; ++mt)
#pragma unroll
        for (int j = 0; j < 4; ++j) {
            float inv = 1.0f / l_run[mt][j];
            int s = qrow0 + mt * 16 + l4 * 4 + j;
#pragma unroll
            for (int dt = 0; dt < 8; ++dt)
                Ctx[(size_t)s * HDIM + h * HEAD_DIM + dt * 16 + l15] = f2bf(o[mt][dt][j] * inv);
        }
}

// ---------- launcher ----------

extern "C" void kernel_launch(void* const* d_in, const int* in_sizes, int n_in,
                              void* d_out, int out_size, void* d_ws, size_t ws_size,
                              hipStream_t stream) {
    const float* hs = (const float*)d_in[0];
    const float* wqkv = (const float*)d_in[1];
    const float* wo = (const float*)d_in[2];
    const int* pos = (const int*)d_in[4];
    float* out = (float*)d_out;
    char* ws = (char*)d_ws;
    const size_t MB = 1024 * 1024;

    unsigned short* hs_b = (unsigned short*)(ws);             // 16 MiB
    unsigned short* wq_t = (unsigned short*)(ws + 16 * MB);   // 96 MiB  [12288][4096]
    unsigned short* wo_t = (unsigned short*)(ws + 112 * MB);  // 32 MiB  [4096][4096]
    unsigned short* qbuf = (unsigned short*)(ws + 144 * MB);  // 16 MiB  [NH][S][HD]
    unsigned short* kbuf = (unsigned short*)(ws + 160 * MB);  // 16 MiB
    unsigned short* vtb  = (unsigned short*)(ws + 176 * MB);  // 16 MiB  [NH][HD][S]
    unsigned short* ctx  = (unsigned short*)(ws + 192 * MB);  // 16 MiB  [S][H]
    float* ctab = (float*)(ws + 208 * MB);                    // 512 KiB
    float* stab = (float*)(ws + 209 * MB);                    // 512 KiB

    cvt_hs_k<<<(S_LEN * HDIM / 4 + 255) / 256, 256, 0, stream>>>(hs, hs_b, S_LEN * HDIM / 4);
    tconv_k<<<dim3(N_QKV / 64, HDIM / 64), 256, 0, stream>>>(wqkv, wq_t, HDIM, N_QKV);
    tconv_k<<<dim3(HDIM / 64, HDIM / 64), 256, 0, stream>>>(wo, wo_t, HDIM, HDIM);
    rope_tab_k<<<(S_LEN * 64) / 256, 256, 0, stream>>>(pos, ctab, stab);
    gemm1_k<<<dim3(N_QKV / 128, S_LEN / 128), 256, 0, stream>>>(hs_b, wq_t, ctab, stab, qbuf, kbuf, vtb);
    flash_k<<<dim3(S_LEN / 128, NHEADS), 256, 0, stream>>>(qbuf, kbuf, vtb, ctx);
    gemm2_k<<<dim3(HDIM / 128, S_LEN / 128), 256, 0, stream>>>(ctx, wo_t, out);
}

// Round 5
// 585.529 us; speedup vs baseline: 1.3082x; 1.1842x over previous
//
#include <hip/hip_runtime.h>

#define S_LEN 2048
#define HDIM 4096
#define NHEADS 32
#define HEAD_DIM 128
#define HALF_DIM 64
#define N_QKV 12288
#define QK_COLS 8192

typedef __attribute__((ext_vector_type(8))) short short8;
typedef __attribute__((ext_vector_type(4))) float f32x4;

typedef const __attribute__((address_space(1))) unsigned int gu32;
typedef __attribute__((address_space(3))) unsigned int lu32;

__device__ __forceinline__ void gload_lds16(const void* g, void* l) {
    __builtin_amdgcn_global_load_lds((gu32*)g, (lu32*)l, 16, 0, 0);
}

__device__ __forceinline__ unsigned short f2bf(float f) {
    unsigned int u = __float_as_uint(f);
    u += 0x7fff + ((u >> 16) & 1);
    return (unsigned short)(u >> 16);
}

// XCD-chunked block remap (bx-fast within each XCD's contiguous chunk).
__device__ __forceinline__ void xcd_map(int& bx, int& by) {
    int gx = gridDim.x;
    int lin = blockIdx.y * gx + blockIdx.x;
    int x = lin & 7, c = lin >> 3;
    int bxp = gx >> 3;  // gridDim.x must be a multiple of 8
    bx = bxp * x + c % bxp;
    by = c / bxp;
}

// ---------- conversion kernels ----------

__global__ __launch_bounds__(256) void cvt_hs_k(const float* __restrict__ in,
                                                unsigned short* __restrict__ out, int n4) {
    int i = blockIdx.x * 256 + threadIdx.x;
    if (i >= n4) return;
    float4 v = reinterpret_cast<const float4*>(in)[i];
    ushort4 o;
    o.x = f2bf(v.x); o.y = f2bf(v.y); o.z = f2bf(v.z); o.w = f2bf(v.w);
    reinterpret_cast<ushort4*>(out)[i] = o;
}

// column permutation for q/k sections: puts RoPE partner (d, d+64) 16 cols apart.
// d = e + 64h (e in [0,64)) -> d2 = (e&15) + 32*(e>>4) + 16*h
__device__ __forceinline__ int permute_col(int n) {
    if (n < QK_COLS) {
        int hd = n & 127;
        int base = n - hd;
        int e = hd & 63;
        int d2 = (e & 15) + 32 * (e >> 4) + ((hd >> 6) << 4);
        return base + d2;
    }
    return n;
}

// in: [R][C] fp32  ->  out: [perm(C)][R] bf16
template <bool PERM>
__global__ __launch_bounds__(256) void tconv_k(const float* __restrict__ in,
                                               unsigned short* __restrict__ out, int R, int C) {
    __shared__ float tile[64][65];
    int c0 = blockIdx.x * 64, r0 = blockIdx.y * 64;
    int tx = threadIdx.x & 63, ty = threadIdx.x >> 6;
#pragma unroll
    for (int i = 0; i < 16; ++i) {
        int r = ty + i * 4;
        tile[r][tx] = in[(size_t)(r0 + r) * C + c0 + tx];
    }
    __syncthreads();
#pragma unroll
    for (int i = 0; i < 16; ++i) {
        int c = ty + i * 4;
        int n = PERM ? permute_col(c0 + c) : (c0 + c);
        out[(size_t)n * R + r0 + tx] = f2bf(tile[tx][c]);
    }
}

// cos/sin tables: [S][64]
__global__ __launch_bounds__(256) void rope_tab_k(const int* __restrict__ pos_raw,
                                                  float* __restrict__ ctab,
                                                  float* __restrict__ stab) {
    int i = blockIdx.x * 256 + threadIdx.x;  // i < S*64
    int s = i >> 6, d = i & 63;
    bool is64 = (pos_raw[1] == 0 && pos_raw[2] == 1);
    int p = is64 ? pos_raw[2 * s] : pos_raw[s];
    const float INVB = -0.14391156831212787f;  // -2*ln(10000)/128
    float freq = expf((float)d * INVB);
    float th = (float)p * freq;
    ctab[i] = cosf(th);
    stab[i] = sinf(th);
}

// ---------- GEMM mainloop (m97-style): 128x128 tile, BK=64, 4 waves (2x2), wave tile 64x64 ----
// SINGLE-buffered LDS 32KB -> 3 blocks/CU; stage -> vmcnt(0) -> barrier -> compute -> barrier.
// Per wave per K-tile: 16 ds_read_b128 + 32 MFMA. T2 XOR swizzle both-sides.

__device__ __forceinline__ void mainloop(const unsigned short* __restrict__ Ag,
                                         const unsigned short* __restrict__ Bg,
                                         int K, int m0, int n0,
                                         char* As, char* Bs,
                                         f32x4 (&acc)[4][4]) {
    const int tid = threadIdx.x;
    const int wid = tid >> 6, lane = tid & 63, l15 = lane & 15, l4 = lane >> 4;
    const int wm = wid >> 1, wn = wid & 1;
    const int NT = K >> 6;

    size_t abase[4], bbase[4];
    int off[4];
#pragma unroll
    for (int i = 0; i < 4; ++i) {
        int p = (i * 256 + tid) << 4;           // LDS byte offset 0..16383
        int q = p ^ (((p >> 7) & 7) << 4);      // inverse swizzle on global source
        abase[i] = (size_t)(m0 + (q >> 7)) * K + ((q & 127) >> 1);
        bbase[i] = (size_t)(n0 + (q >> 7)) * K + ((q & 127) >> 1);
        off[i] = p;
    }

    for (int t = 0; t < NT; ++t) {
        int k0 = t << 6;
#pragma unroll
        for (int i = 0; i < 4; ++i) gload_lds16(Ag + abase[i] + k0, As + off[i]);
#pragma unroll
        for (int i = 0; i < 4; ++i) gload_lds16(Bg + bbase[i] + k0, Bs + off[i]);
        asm volatile("s_waitcnt vmcnt(0)" ::: "memory");
        __builtin_amdgcn_s_barrier();

        short8 a[4][2], b[4][2];
#pragma unroll
        for (int am = 0; am < 4; ++am)
#pragma unroll
            for (int ks = 0; ks < 2; ++ks) {
                int lin = ((wm * 64 + am * 16 + l15) << 7) + ks * 64 + l4 * 16;
                a[am][ks] = *(const short8*)(As + (lin ^ (((lin >> 7) & 7) << 4)));
            }
#pragma unroll
        for (int bn = 0; bn < 4; ++bn)
#pragma unroll
            for (int ks = 0; ks < 2; ++ks) {
                int lin = ((wn * 64 + bn * 16 + l15) << 7) + ks * 64 + l4 * 16;
                b[bn][ks] = *(const short8*)(Bs + (lin ^ (((lin >> 7) & 7) << 4)));
            }
#pragma unroll
        for (int ks = 0; ks < 2; ++ks)
#pragma unroll
            for (int am = 0; am < 4; ++am)
#pragma unroll
                for (int bn = 0; bn < 4; ++bn)
                    acc[am][bn] = __builtin_amdgcn_mfma_f32_16x16x32_bf16(a[am][ks], b[bn][ks], acc[am][bn], 0, 0, 0);

        __builtin_amdgcn_s_barrier();  // all reads done before next stage overwrites
    }
}

// GEMM1: qkv = hs @ W_qkv (q/k cols permuted), fused RoPE epilogue
__global__ __launch_bounds__(256, 3) void gemm1_k(const unsigned short* __restrict__ A,
                                                  const unsigned short* __restrict__ Bt,
                                                  const float* __restrict__ ctab,
                                                  const float* __restrict__ stab,
                                                  unsigned short* __restrict__ qb,
                                                  unsigned short* __restrict__ kb,
                                                  unsigned short* __restrict__ vt) {
    __shared__ __attribute__((aligned(16))) char As[16384];
    __shared__ __attribute__((aligned(16))) char Bs[16384];

    int bx, by;
    xcd_map(bx, by);
    int m0 = by * 128, n0 = bx * 128;

    f32x4 acc[4][4];
#pragma unroll
    for (int i = 0; i < 4; ++i)
#pragma unroll
        for (int j = 0; j < 4; ++j) acc[i][j] = (f32x4){0.f, 0.f, 0.f, 0.f};

    mainloop(A, Bt, HDIM, m0, n0, As, Bs, acc);

    int tid = threadIdx.x, wid = tid >> 6, lane = tid & 63, l15 = lane & 15, l4 = lane >> 4;
    int wm = wid >> 1, wn = wid & 1;
    int which = n0 >> 12;  // 0=q 1=k 2=v  (128-tile never crosses a 4096 boundary)
    int head = (n0 & 4095) >> 7;
    if (which < 2) {
        unsigned short* dst = which ? kb : qb;
#pragma unroll
        for (int am = 0; am < 4; ++am)
#pragma unroll
            for (int j = 0; j < 4; ++j) {
                int s = m0 + wm * 64 + am * 16 + l4 * 4 + j;
#pragma unroll
                for (int p = 0; p < 2; ++p) {
                    // permuted col d2 = wn*64 + bn*16 + l15, bn = 2p (h=0) / 2p+1 (h=1)
                    float x1 = acc[am][2 * p][j], x2 = acc[am][2 * p + 1][j];
                    int e = l15 + 16 * (2 * wn + p);
                    float cs = ctab[s * 64 + e], sn = stab[s * 64 + e];
                    dst[((size_t)head * S_LEN + s) * HEAD_DIM + e] = f2bf(x1 * cs - x2 * sn);
                    dst[((size_t)head * S_LEN + s) * HEAD_DIM + e + 64] = f2bf(x1 * sn + x2 * cs);
                }
            }
    } else {
#pragma unroll
        for (int am = 0; am < 4; ++am)
#pragma unroll
            for (int j = 0; j < 4; ++j) {
                int s = m0 + wm * 64 + am * 16 + l4 * 4 + j;
#pragma unroll
                for (int bn = 0; bn < 4; ++bn) {
                    int d = wn * 64 + bn * 16 + l15;
                    vt[((size_t)head * HEAD_DIM + d) * S_LEN + s] = f2bf(acc[am][bn][j]);
                }
            }
    }
}

// GEMM2: out = ctx @ W_o (fp32 out)
__global__ __launch_bounds__(256, 3) void gemm2_k(const unsigned short* __restrict__ A,
                                                  const unsigned short* __restrict__ Bt,
                                                  float* __restrict__ out) {
    __shared__ __attribute__((aligned(16))) char As[16384];
    __shared__ __attribute__((aligned(16))) char Bs[16384];

    int bx, by;
    xcd_map(bx, by);
    int m0 = by * 128, n0 = bx * 128;

    f32x4 acc[4][4];
#pragma unroll
    for (int i = 0; i < 4; ++i)
#pragma unroll
        for (int j = 0; j < 4; ++j) acc[i][j] = (f32x4){0.f, 0.f, 0.f, 0.f};

    mainloop(A, Bt, HDIM, m0, n0, As, Bs, acc);

    int tid = threadIdx.x, wid = tid >> 6, lane = tid & 63, l15 = lane & 15, l4 = lane >> 4;
    int wm = wid >> 1, wn = wid & 1;
#pragma unroll
    for (int am = 0; am < 4; ++am)
#pragma unroll
        for (int j = 0; j < 4; ++j) {
            int s = m0 + wm * 64 + am * 16 + l4 * 4 + j;
#pragma unroll
            for (int bn = 0; bn < 4; ++bn)
                out[(size_t)s * HDIM + n0 + wn * 64 + bn * 16 + l15] = acc[am][bn][j];
        }
}

// ---------- flash attention (frozen) ----------
__global__ __launch_bounds__(256) void flash_k(const unsigned short* __restrict__ Q,
                                               const unsigned short* __restrict__ Kb,
                                               const unsigned short* __restrict__ Vt,
                                               unsigned short* __restrict__ Ctx) {
    __shared__ __attribute__((aligned(16))) unsigned short Ks[32 * 128];
    __shared__ __attribute__((aligned(16))) unsigned short Vs[128 * 32];
    __shared__ __attribute__((aligned(16))) unsigned short Ps[4][32 * 32];
    int qbk = blockIdx.x, h = blockIdx.y;
    int tid = threadIdx.x, w = tid >> 6, lane = tid & 63, l15 = lane & 15, l4 = lane >> 4;
    int qrow0 = qbk * 128 + w * 32;

    short8 qf[2][4];
#pragma unroll
    for (int mt = 0; mt < 2; ++mt) {
        int s = qrow0 + mt * 16 + l15;
#pragma unroll
        for (int ks = 0; ks < 4; ++ks)
            qf[mt][ks] = *(const short8*)(Q + ((size_t)h * S_LEN + s) * HEAD_DIM + ks * 32 + l4 * 8);
    }

    float m_run[2][4], l_run[2][4];
    f32x4 o[2][8];
#pragma unroll
    for (int mt = 0; mt < 2; ++mt)
#pragma unroll
        for (int j = 0; j < 4; ++j) { m_run[mt][j] = -1e30f; l_run[mt][j] = 0.f; }
#pragma unroll
    for (int mt = 0; mt < 2; ++mt)
#pragma unroll
        for (int dt = 0; dt < 8; ++dt) o[mt][dt] = (f32x4){0.f, 0.f, 0.f, 0.f};

    const float scale = 0.08838834764831845f;  // 1/sqrt(128)
    int ntiles = (qbk + 1) * 4;

    for (int t = 0; t < ntiles; ++t) {
        __syncthreads();
#pragma unroll
        for (int it = 0; it < 2; ++it) {
            int idx = it * 256 + tid;
            int kr = idx >> 4, kc = (idx & 15) << 3;
            gload_lds16(Kb + ((size_t)h * S_LEN + t * 32 + kr) * HEAD_DIM + kc, Ks + idx * 8);
            int vr = idx >> 2, vc = (idx & 3) << 3;
            gload_lds16(Vt + ((size_t)h * HEAD_DIM + vr) * S_LEN + t * 32 + vc, Vs + idx * 8);
        }
        __syncthreads();

        f32x4 sc[2][2];
#pragma unroll
        for (int mt = 0; mt < 2; ++mt)
#pragma unroll
            for (int nt = 0; nt < 2; ++nt) sc[mt][nt] = (f32x4){0.f, 0.f, 0.f, 0.f};
#pragma unroll
        for (int ks = 0; ks < 4; ++ks) {
            short8 kfr[2];
#pragma unroll
            for (int nt = 0; nt < 2; ++nt)
                kfr[nt] = *(const short8*)(Ks + (nt * 16 + l15) * 128 + ks * 32 + l4 * 8);
#pragma unroll
            for (int mt = 0; mt < 2; ++mt)
#pragma unroll
                for (int nt = 0; nt < 2; ++nt)
                    sc[mt][nt] = __builtin_amdgcn_mfma_f32_16x16x32_bf16(qf[mt][ks], kfr[nt], sc[mt][nt], 0, 0, 0);
        }

#pragma unroll
        for (int mt = 0; mt < 2; ++mt)
#pragma unroll
            for (int j = 0; j < 4; ++j) {
                int srow = qrow0 + mt * 16 + l4 * 4 + j;
                float v0 = sc[mt][0][j] * scale;
                float v1 = sc[mt][1][j] * scale;
                int c0 = t * 32 + l15;
                if (c0 > srow) v0 = -1e30f;
                if (c0 + 16 > srow) v1 = -1e30f;
                float mx = fmaxf(v0, v1);
                mx = fmaxf(mx, __shfl_xor(mx, 1));
                mx = fmaxf(mx, __shfl_xor(mx, 2));
                mx = fmaxf(mx, __shfl_xor(mx, 4));
                mx = fmaxf(mx, __shfl_xor(mx, 8));
                float mold = m_run[mt][j];
                float mnew = fmaxf(mold, mx);
                float r = __expf(mold - mnew);
                float p0 = __expf(v0 - mnew);
                float p1 = __expf(v1 - mnew);
                float rs = p0 + p1;
                rs += __shfl_xor(rs, 1);
                rs += __shfl_xor(rs, 2);
                rs += __shfl_xor(rs, 4);
                rs += __shfl_xor(rs, 8);
                m_run[mt][j] = mnew;
                l_run[mt][j] = l_run[mt][j] * r + rs;
#pragma unroll
                for (int dt = 0; dt < 8; ++dt) o[mt][dt][j] *= r;
                int prow = mt * 16 + l4 * 4 + j;
                Ps[w][prow * 32 + l15] = f2bf(p0);
                Ps[w][prow * 32 + l15 + 16] = f2bf(p1);
            }
        __syncthreads();

        short8 pf[2];
#pragma unroll
        for (int mt = 0; mt < 2; ++mt)
            pf[mt] = *(const short8*)(&Ps[w][(mt * 16 + l15) * 32 + l4 * 8]);
#pragma unroll
        for (int dt = 0; dt < 8; ++dt) {
            short8 vf = *(const short8*)(Vs + (dt * 16 + l15) * 32 + l4 * 8);
#pragma unroll
            for (int mt = 0; mt < 2; ++mt)
                o[mt][dt] = __builtin_amdgcn_mfma_f32_16x16x32_bf16(pf[mt], vf, o[mt][dt], 0, 0, 0);
        }
    }

#pragma unroll
    for (int mt = 0; mt < 2; ++mt)
#pragma unroll
        for (int j = 0; j < 4; ++j) {
            float inv = 1.0f / l_run[mt][j];
            int s = qrow0 + mt * 16 + l4 * 4 + j;
#pragma unroll
            for (int dt = 0; dt < 8; ++dt)
                Ctx[(size_t)s * HDIM + h * HEAD_DIM + dt * 16 + l15] = f2bf(o[mt][dt][j] * inv);
        }
}

// ---------- launcher ----------

extern "C" void kernel_launch(void* const* d_in, const int* in_sizes, int n_in,
                              void* d_out, int out_size, void* d_ws, size_t ws_size,
                              hipStream_t stream) {
    const float* hs = (const float*)d_in[0];
    const float* wqkv = (const float*)d_in[1];
    const float* wo = (const float*)d_in[2];
    const int* pos = (const int*)d_in[4];
    float* out = (float*)d_out;
    char* ws = (char*)d_ws;
    const size_t MB = 1024 * 1024;

    unsigned short* hs_b = (unsigned short*)(ws);             // 16 MiB
    unsigned short* wq_t = (unsigned short*)(ws + 16 * MB);   // 96 MiB  [12288][4096] (q/k cols permuted)
    unsigned short* wo_t = (unsigned short*)(ws + 112 * MB);  // 32 MiB  [4096][4096]
    unsigned short* qbuf = (unsigned short*)(ws + 144 * MB);  // 16 MiB  [NH][S][HD]
    unsigned short* kbuf = (unsigned short*)(ws + 160 * MB);  // 16 MiB
    unsigned short* vtb  = (unsigned short*)(ws + 176 * MB);  // 16 MiB  [NH][HD][S]
    unsigned short* ctx  = (unsigned short*)(ws + 192 * MB);  // 16 MiB  [S][H]
    float* ctab = (float*)(ws + 208 * MB);                    // 512 KiB
    float* stab = (float*)(ws + 209 * MB);                    // 512 KiB

    cvt_hs_k<<<(S_LEN * HDIM / 4 + 255) / 256, 256, 0, stream>>>(hs, hs_b, S_LEN * HDIM / 4);
    tconv_k<true><<<dim3(N_QKV / 64, HDIM / 64), 256, 0, stream>>>(wqkv, wq_t, HDIM, N_QKV);
    tconv_k<false><<<dim3(HDIM / 64, HDIM / 64), 256, 0, stream>>>(wo, wo_t, HDIM, HDIM);
    rope_tab_k<<<(S_LEN * 64) / 256, 256, 0, stream>>>(pos, ctab, stab);
    gemm1_k<<<dim3(N_QKV / 128, S_LEN / 128), 256, 0, stream>>>(hs_b, wq_t, ctab, stab, qbuf, kbuf, vtb);
    flash_k<<<dim3(S_LEN / 128, NHEADS), 256, 0, stream>>>(qbuf, kbuf, vtb, ctx);
    gemm2_k<<<dim3(HDIM / 128, S_LEN / 128), 256, 0, stream>>>(ctx, wo_t, out);
}